// Round 5
// baseline (13735.382 us; speedup 1.0000x reference)
//
#include <hip/hip_runtime.h>
#include <hip/hip_bf16.h>
#include <stdint.h>

#define LL 4096
#define EE 300
#define HH 512
#define G4H 2048
#define TT 11
#define TSTART 9
#define TSTOP 10
#define NEGINF -10000.0f

typedef unsigned long long u64;

__device__ __forceinline__ float sigf(float x){
    x = fminf(fmaxf(x, -30.f), 30.f);
    return 1.0f / (1.0f + __expf(-x));
}
__device__ __forceinline__ float tanhfast(float x){
    x = fminf(fmaxf(x, -15.f), 15.f);
    float e = __expf(-2.0f * x);
    return (1.0f - e) / (1.0f + e);
}
__device__ __forceinline__ u64 shfl_u64(u64 v, int src){
    unsigned lo = (unsigned)v, hi = (unsigned)(v >> 32);
    lo = __shfl(lo, src, 64); hi = __shfl(hi, src, 64);
    return ((u64)hi << 32) | (u64)lo;
}
__device__ __forceinline__ u64 lda(const u64* p){
    return __hip_atomic_load(p, __ATOMIC_RELAXED, __HIP_MEMORY_SCOPE_AGENT);
}
__device__ __forceinline__ u64 ldwg(const u64* p){
    return __hip_atomic_load(p, __ATOMIC_RELAXED, __HIP_MEMORY_SCOPE_WORKGROUP);
}
__device__ __forceinline__ void stwg(u64* p, u64 v){
    __hip_atomic_store(p, v, __ATOMIC_RELAXED, __HIP_MEMORY_SCOPE_WORKGROUP);
}

// ---------------- K0: zero the h-communication buffers (fresh tags each call)
__global__ void k0_zero(u64* __restrict__ comm){
    int i = blockIdx.x * blockDim.x + threadIdx.x;
    if (i < 2 * 2 * HH) comm[i] = 0ull;
}

// ---------------- K1: xg[dir][t][r] = emb[sent[t]] . w_ih[dir][r] + b_ih[r] + b_hh[r]
__global__ __launch_bounds__(256) void k1_xg(
    const int* __restrict__ sent, const float* __restrict__ emb,
    const float* __restrict__ wih_f, const float* __restrict__ bih_f, const float* __restrict__ bhh_f,
    const float* __restrict__ wih_b, const float* __restrict__ bih_b, const float* __restrict__ bhh_b,
    float* __restrict__ xg_f, float* __restrict__ xg_b)
{
    __shared__ float elds[32 * 304];
    int t0  = blockIdx.x * 32;
    int r0  = blockIdx.y * 256;
    int dir = blockIdx.z;
    const float* wih = dir ? wih_b : wih_f;
    const float* bih = dir ? bih_b : bih_f;
    const float* bhh = dir ? bhh_b : bhh_f;
    float* xg = dir ? xg_b : xg_f;

    for (int idx = threadIdx.x; idx < 32 * EE; idx += 256){
        int i = idx / EE, e = idx - i * EE;
        elds[i * 304 + e] = emb[(long)sent[t0 + i] * EE + e];
    }
    __syncthreads();

    int rA = r0 + (threadIdx.x & 127);
    int rB = rA + 128;
    int half = threadIdx.x >> 7;
    float accA[16], accB[16];
    #pragma unroll
    for (int i = 0; i < 16; i++){ accA[i] = 0.f; accB[i] = 0.f; }
    const float* wrowA = wih + (long)rA * EE;
    const float* wrowB = wih + (long)rB * EE;
    for (int e4 = 0; e4 < 75; e4++){
        float4 wa = *reinterpret_cast<const float4*>(wrowA + e4 * 4);
        float4 wb = *reinterpret_cast<const float4*>(wrowB + e4 * 4);
        #pragma unroll
        for (int i = 0; i < 16; i++){
            float4 ev = *reinterpret_cast<const float4*>(&elds[(half * 16 + i) * 304 + e4 * 4]);
            accA[i] += wa.x * ev.x + wa.y * ev.y + wa.z * ev.z + wa.w * ev.w;
            accB[i] += wb.x * ev.x + wb.y * ev.y + wb.z * ev.z + wb.w * ev.w;
        }
    }
    float bA = bih[rA] + bhh[rA];
    float bB = bih[rB] + bhh[rB];
    #pragma unroll
    for (int i = 0; i < 16; i++){
        int t = t0 + half * 16 + i;
        xg[(long)t * G4H + rA] = accA[i] + bA;
        xg[(long)t * G4H + rB] = accB[i] + bB;
    }
}

// ---------------- K2: persistent BiLSTM — barrier-free LDS-tag redistribution +
// reduce-scatter butterfly. 64 blocks x 512 thr; bid>>5 = dir, b = bid&31 owns
// j [16b, 16b+16); wave w owns outputs {16b+2w, 16b+2w+1}.
// Per step: thread tid spin-polls global comm word tid (tagged u64), ds-stores
// it (tagged) to hlds; consumers spin on LDS tags (no __syncthreads at all).
// Row map r' = jp*4 + g so one output's 4 gates land on adjacent lanes;
// reduce-scatter (4+2+1 shfl) + 3-stage allreduce + 4 gather shfl; gate math
// exec-uniform on all 64 lanes; lanes 0/4 publish (global + hs + own-LDS).
__global__ __launch_bounds__(512) void k2_lstm(
    const float* __restrict__ whh_f, const float* __restrict__ whh_b,
    const float* __restrict__ xg_f, const float* __restrict__ xg_b,
    float* __restrict__ hs_f, float* __restrict__ hs_b,
    u64* __restrict__ comm)
{
    int dir = blockIdx.x >> 5;
    int b   = blockIdx.x & 31;
    int j0  = b * 16;
    int tid = threadIdx.x;
    int w   = tid >> 6;
    int l   = tid & 63;
    int jA  = j0 + 2 * w;
    int jp  = (l >> 2) & 1;       // output parity this lane's gates belong to
    int b0  = l & 1, b1 = (l >> 1) & 1, b2 = jp;

    const float* whh = dir ? whh_b : whh_f;
    const float* xg  = dir ? xg_b  : xg_f;
    float* hs        = dir ? hs_b  : hs_f;
    u64* cm          = comm + dir * 2 * HH;

    // wreg[r][k]: r = jp*4 + g -> global row (r&3)*HH + jA + (r>>2), col k*64+l
    float wreg[8][8];
    #pragma unroll
    for (int r = 0; r < 8; r++){
        const float* wp = whh + (size_t)((r & 3) * HH + jA + (r >> 2)) * HH + l;
        #pragma unroll
        for (int k = 0; k < 8; k++) wreg[r][k] = wp[k * 64];
    }

    __shared__ u64 hlds[2][HH];
    hlds[0][tid] = 0ull;
    hlds[1][tid] = 0ull;
    __syncthreads();  // once, before the loop (LDS tag init)

    bool remote = (tid < j0) || (tid >= j0 + 16);
    float c = 0.f;

    for (int s = 0; s < LL; ++s){
        int t = dir ? (LL - 1 - s) : s;

        // xg for this lane's row (gate l&3, output jA+jp); in flight during poll
        float xgd = xg[(size_t)t * G4H + (l & 3) * HH + jA + jp];

        float h[8];
        if (s == 0){
            #pragma unroll
            for (int k = 0; k < 8; k++) h[k] = 0.f;
        } else {
            // poll my global word (remote only; own-block words arrive via LDS)
            if (remote){
                const u64* pw = cm + (s & 1) * HH + tid;
                u64 v = lda(pw);
                while ((unsigned)(v >> 32) != (unsigned)s) v = lda(pw);
                stwg(&hlds[s & 1][tid], v);
            }
            // consume: spin on the 8 LDS tags this lane needs
            u64 vv[8];
            #pragma unroll
            for (int k = 0; k < 8; k++) vv[k] = ldwg(&hlds[s & 1][k * 64 + l]);
            unsigned want = (unsigned)s;
            for (;;){
                unsigned bad = 0;
                #pragma unroll
                for (int k = 0; k < 8; k++) bad |= ((unsigned)(vv[k] >> 32)) ^ want;
                if (__all(bad == 0)) break;
                #pragma unroll
                for (int k = 0; k < 8; k++)
                    if ((unsigned)(vv[k] >> 32) != want)
                        vv[k] = ldwg(&hlds[s & 1][k * 64 + l]);
            }
            #pragma unroll
            for (int k = 0; k < 8; k++) h[k] = __uint_as_float((unsigned)vv[k]);
        }

        // per-lane dot: acc[r] = sum_k wreg[r][k] * h[k]
        float acc[8];
        #pragma unroll
        for (int r = 0; r < 8; r++){
            float a0 = wreg[r][0] * h[0] + wreg[r][1] * h[1];
            float a1 = wreg[r][2] * h[2] + wreg[r][3] * h[3];
            float a2 = wreg[r][4] * h[4] + wreg[r][5] * h[5];
            float a3 = wreg[r][6] * h[6] + wreg[r][7] * h[7];
            acc[r] = (a0 + a1) + (a2 + a3);
        }

        // reduce-scatter: stage 1 (xor 1) -- keep rows with r&1 == b0
        float t1[4];
        #pragma unroll
        for (int m = 0; m < 4; m++){
            float tx = b0 ? acc[2 * m]     : acc[2 * m + 1];  // what partner keeps
            float kp = b0 ? acc[2 * m + 1] : acc[2 * m];      // what I keep
            t1[m] = kp + __shfl_xor(tx, 1, 64);               // rows 2m + b0
        }
        // stage 2 (xor 2) -- keep m&1 == b1
        float t2[2];
        #pragma unroll
        for (int m = 0; m < 2; m++){
            float tx = b1 ? t1[2 * m]     : t1[2 * m + 1];
            float kp = b1 ? t1[2 * m + 1] : t1[2 * m];
            t2[m] = kp + __shfl_xor(tx, 2, 64);               // rows 4m + 2b1 + b0
        }
        // stage 3 (xor 4) -- keep m == b2
        float tx3 = b2 ? t2[0] : t2[1];
        float kp3 = b2 ? t2[1] : t2[0];
        float d = kp3 + __shfl_xor(tx3, 4, 64);               // row l&7, 8-lane partial
        // allreduce across the 8 lane-groups
        d += __shfl_xor(d, 8, 64);
        d += __shfl_xor(d, 16, 64);
        d += __shfl_xor(d, 32, 64);
        // d = full preact of row l&7 (gate l&3, output jA+jp)

        float pre = d + xgd;
        // gather the 4 gates of my output (adjacent lanes base..base+3)
        int base = l & 60;
        float vi = __shfl(pre, base,     64);
        float vf = __shfl(pre, base + 1, 64);
        float vg = __shfl(pre, base + 2, 64);
        float vo = __shfl(pre, base + 3, 64);
        // exec-uniform gate math; all lanes with equal jp compute identical c,h
        c = sigf(vf) * c + sigf(vi) * tanhfast(vg);
        float hv = sigf(vo) * tanhfast(c);

        if (l == 0 || l == 4){
            int j = jA + jp;
            union { float f; unsigned u; } cv; cv.f = hv;
            u64 pk = ((u64)(s + 1) << 32) | (u64)cv.u;
            __hip_atomic_store(cm + ((s + 1) & 1) * HH + j, pk,
                               __ATOMIC_RELAXED, __HIP_MEMORY_SCOPE_AGENT);
            stwg(&hlds[(s + 1) & 1][j], pk);   // own-block fast path
            hs[(size_t)t * HH + j] = hv;
        }
    }
}

// ---------------- K3: feats[t][n] = w_tag[n] . [hf[t], hb[t]] + b_tag[n]
__global__ __launch_bounds__(64) void k3_feats(
    const float* __restrict__ hs_f, const float* __restrict__ hs_b,
    const float* __restrict__ wtag, const float* __restrict__ btag,
    float* __restrict__ feats)
{
    int t = blockIdx.x;
    int lane = threadIdx.x;
    float hreg[16];
    #pragma unroll
    for (int q = 0; q < 16; q++){
        int k = q * 64 + lane;
        hreg[q] = (q < 8) ? hs_f[(long)t * HH + k] : hs_b[(long)t * HH + (k - HH)];
    }
    for (int n = 0; n < TT; n++){
        float a = 0.f;
        #pragma unroll
        for (int q = 0; q < 16; q++){
            a += wtag[n * 1024 + q * 64 + lane] * hreg[q];
        }
        #pragma unroll
        for (int off = 32; off; off >>= 1) a += __shfl_down(a, off, 64);
        if (lane == 0) feats[t * 12 + n] = a + btag[n];
    }
}

// ---------------- K4: Viterbi scan + backtrace on a single wave
__global__ __launch_bounds__(64) void k4_viterbi(
    const float* __restrict__ feats, const float* __restrict__ trans,
    float* __restrict__ out)
{
    __shared__ u64 bplds[LL];
    int lane = threadIdx.x;
    float tr[TT];
    #pragma unroll
    for (int p = 0; p < TT; p++) tr[p] = (lane < TT) ? trans[lane * TT + p] : NEGINF;
    float fv = (lane == TSTART) ? 0.f : NEGINF;

    #define LDF(t) ((lane < TT) ? feats[(t) * 12 + lane] : 0.f)
    float f0 = LDF(0), f1 = LDF(1), f2 = LDF(2), f3 = LDF(3);

    for (int t = 0; t < LL; t += 4){
        #define VSTEP(FT, TNEXT, TCUR) { \
            float best = __shfl(fv, 0, 64) + tr[0]; int bp = 0; \
            _Pragma("unroll") \
            for (int p = 1; p < TT; p++){ \
                float sp = __shfl(fv, p, 64) + tr[p]; \
                if (sp > best){ best = sp; bp = p; } \
            } \
            unsigned lo = (lane < 8) ? ((unsigned)bp << (4 * lane)) : 0u; \
            unsigned hi = (lane >= 8 && lane < TT) ? ((unsigned)bp << (4 * (lane - 8))) : 0u; \
            _Pragma("unroll") \
            for (int off = 1; off < 16; off <<= 1){ \
                lo |= __shfl_xor(lo, off, 16); hi |= __shfl_xor(hi, off, 16); \
            } \
            if (lane == 0) bplds[TCUR] = (u64)lo | ((u64)hi << 32); \
            fv = best + FT; \
            FT = ((TNEXT) < LL) ? LDF(TNEXT) : 0.f; \
        }
        VSTEP(f0, t + 4, t)
        VSTEP(f1, t + 5, t + 1)
        VSTEP(f2, t + 6, t + 2)
        VSTEP(f3, t + 7, t + 3)
        #undef VSTEP
    }
    __syncthreads();

    float term = (lane < TT) ? (fv + trans[TSTOP * TT + lane]) : -3.0e38f;
    int idx = (lane < TT) ? lane : 63;
    #pragma unroll
    for (int off = 32; off; off >>= 1){
        float os = __shfl_down(term, off, 64);
        int   oi = __shfl_down(idx,  off, 64);
        if (os > term || (os == term && oi < idx)){ term = os; idx = oi; }
    }
    term = __shfl(term, 0, 64);
    idx  = __shfl(idx,  0, 64);
    if (lane == 0){
        out[0] = term;                  // path_score
        out[1 + (LL - 1)] = (float)idx; // path[L-1]
    }

    // backtrace: bp table register-resident (lane holds bplds[i*64+lane])
    u64 bpr[64];
    #pragma unroll
    for (int i = 0; i < 64; i++) bpr[i] = bplds[i * 64 + lane];
    int tag = idx;
    #pragma unroll
    for (int i = 63; i >= 0; --i){
        for (int l2 = 63; l2 >= 0; --l2){
            int u = i * 64 + l2;
            if (u == 0) break;
            u64 wv = shfl_u64(bpr[i], l2);
            tag = (int)((wv >> (4 * tag)) & 15ull);
            if (lane == 0) out[u] = (float)tag;  // out[1 + (u-1)]
        }
    }
}

__global__ void k_dbg(float* out, float v){ out[0] = v; }

extern "C" void kernel_launch(void* const* d_in, const int* in_sizes, int n_in,
                              void* d_out, int out_size, void* d_ws, size_t ws_size,
                              hipStream_t stream)
{
    const int*   sent  = (const int*)  d_in[0];
    const float* emb   = (const float*)d_in[1];
    const float* wih_f = (const float*)d_in[2];
    const float* whh_f = (const float*)d_in[3];
    const float* bih_f = (const float*)d_in[4];
    const float* bhh_f = (const float*)d_in[5];
    const float* wih_b = (const float*)d_in[6];
    const float* whh_b = (const float*)d_in[7];
    const float* bih_b = (const float*)d_in[8];
    const float* bhh_b = (const float*)d_in[9];
    const float* wtag  = (const float*)d_in[10];
    const float* btag  = (const float*)d_in[11];
    const float* trans = (const float*)d_in[12];
    float* out = (float*)d_out;

    char* ws = (char*)d_ws;
    size_t off = 0;
    float* xg_f = (float*)(ws + off); off += (size_t)LL * G4H * 4;
    float* xg_b = (float*)(ws + off); off += (size_t)LL * G4H * 4;
    float* hs_f = (float*)(ws + off); off += (size_t)LL * HH * 4;
    float* hs_b = (float*)(ws + off); off += (size_t)LL * HH * 4;
    float* feats= (float*)(ws + off); off += (size_t)LL * 12 * 4;
    u64* comm   = (u64*)(ws + off);   off += 2 * 2 * HH * 8;

    if (off > ws_size){
        k_dbg<<<1, 1, 0, stream>>>(out, (float)ws_size);
        return;
    }

    k0_zero<<<8, 256, 0, stream>>>(comm);
    k1_xg<<<dim3(128, 8, 2), 256, 0, stream>>>(sent, emb, wih_f, bih_f, bhh_f,
                                               wih_b, bih_b, bhh_b, xg_f, xg_b);
    k2_lstm<<<64, 512, 0, stream>>>(whh_f, whh_b, xg_f, xg_b, hs_f, hs_b, comm);
    k3_feats<<<LL, 64, 0, stream>>>(hs_f, hs_b, wtag, btag, feats);
    k4_viterbi<<<1, 64, 0, stream>>>(feats, trans, out);
}

// Round 6
// 7870.631 us; speedup vs baseline: 1.7451x; 1.7451x over previous
//
#include <hip/hip_runtime.h>
#include <hip/hip_bf16.h>
#include <stdint.h>

#define LL 4096
#define EE 300
#define HH 512
#define G4H 2048
#define TT 11
#define TSTART 9
#define TSTOP 10
#define NEGINF -10000.0f

typedef unsigned long long u64;
typedef short short8 __attribute__((ext_vector_type(8)));
typedef float f32x4 __attribute__((ext_vector_type(4)));

__device__ __forceinline__ float sigf(float x){
    x = fminf(fmaxf(x, -30.f), 30.f);
    return 1.0f / (1.0f + __expf(-x));
}
__device__ __forceinline__ float tanhfast(float x){
    x = fminf(fmaxf(x, -15.f), 15.f);
    float e = __expf(-2.0f * x);
    return (1.0f - e) / (1.0f + e);
}
__device__ __forceinline__ u64 lda(const u64* p){
    return __hip_atomic_load(p, __ATOMIC_RELAXED, __HIP_MEMORY_SCOPE_AGENT);
}
__device__ __forceinline__ unsigned f2bf(float f){   // RNE f32->bf16 (no inf/nan expected)
    unsigned u = __float_as_uint(f);
    return ((u + 0x7FFFu + ((u >> 16) & 1u)) >> 16) & 0xFFFFu;
}

// ---------------- K0: zero the h-communication buffers (fresh tags each call)
__global__ void k0_zero(u64* __restrict__ comm){
    int i = blockIdx.x * blockDim.x + threadIdx.x;
    if (i < 2 * 2 * HH) comm[i] = 0ull;
}

// ---------------- K1: xg[dir][t][r] = emb[sent[t]] . w_ih[dir][r] + b_ih[r] + b_hh[r]
__global__ __launch_bounds__(256) void k1_xg(
    const int* __restrict__ sent, const float* __restrict__ emb,
    const float* __restrict__ wih_f, const float* __restrict__ bih_f, const float* __restrict__ bhh_f,
    const float* __restrict__ wih_b, const float* __restrict__ bih_b, const float* __restrict__ bhh_b,
    float* __restrict__ xg_f, float* __restrict__ xg_b)
{
    __shared__ float elds[32 * 304];
    int t0  = blockIdx.x * 32;
    int r0  = blockIdx.y * 256;
    int dir = blockIdx.z;
    const float* wih = dir ? wih_b : wih_f;
    const float* bih = dir ? bih_b : bih_f;
    const float* bhh = dir ? bhh_b : bhh_f;
    float* xg = dir ? xg_b : xg_f;

    for (int idx = threadIdx.x; idx < 32 * EE; idx += 256){
        int i = idx / EE, e = idx - i * EE;
        elds[i * 304 + e] = emb[(long)sent[t0 + i] * EE + e];
    }
    __syncthreads();

    int rA = r0 + (threadIdx.x & 127);
    int rB = rA + 128;
    int half = threadIdx.x >> 7;
    float accA[16], accB[16];
    #pragma unroll
    for (int i = 0; i < 16; i++){ accA[i] = 0.f; accB[i] = 0.f; }
    const float* wrowA = wih + (long)rA * EE;
    const float* wrowB = wih + (long)rB * EE;
    for (int e4 = 0; e4 < 75; e4++){
        float4 wa = *reinterpret_cast<const float4*>(wrowA + e4 * 4);
        float4 wb = *reinterpret_cast<const float4*>(wrowB + e4 * 4);
        #pragma unroll
        for (int i = 0; i < 16; i++){
            float4 ev = *reinterpret_cast<const float4*>(&elds[(half * 16 + i) * 304 + e4 * 4]);
            accA[i] += wa.x * ev.x + wa.y * ev.y + wa.z * ev.z + wa.w * ev.w;
            accB[i] += wb.x * ev.x + wb.y * ev.y + wb.z * ev.z + wb.w * ev.w;
        }
    }
    float bA = bih[rA] + bhh[rA];
    float bB = bih[rB] + bhh[rB];
    #pragma unroll
    for (int i = 0; i < 16; i++){
        int t = t0 + half * 16 + i;
        xg[(long)t * G4H + rA] = accA[i] + bA;
        xg[(long)t * G4H + rB] = accB[i] + bB;
    }
}

// ---------------- K2: persistent BiLSTM — R1 poll + MFMA dot + in-lane gates.
// 64 blocks x 256 thr (4 waves). bid>>5 = dir, b = bid&31 owns j [16b,16b+16).
// Wave v owns j {j0+4v .. j0+4v+3} (16 rows: r = jloc*4+gate, M=16 tile).
// h replicated across all 16 MFMA B-columns => C col-replication puts the 4
// gate preacts of j = j0+4v+(l>>4) into lane l's 4 acc regs: gates fully
// in-lane, no reduce, no plds. Publish from lanes (l&15)==0.
// Poll: thread tid polls 2 contiguous comm words (tagged u64), converts to
// bf16 pair in LDS. ONE barrier/step.
__global__ __launch_bounds__(256) void k2_lstm(
    const float* __restrict__ whh_f, const float* __restrict__ whh_b,
    const float* __restrict__ xg_f, const float* __restrict__ xg_b,
    float* __restrict__ hs_f, float* __restrict__ hs_b,
    u64* __restrict__ comm)
{
    int dir = blockIdx.x >> 5;
    int b   = blockIdx.x & 31;
    int j0  = b * 16;
    int tid = threadIdx.x;
    int v   = tid >> 6;
    int l   = tid & 63;
    int grp = l >> 4;                 // 0..3
    int jmine = j0 + v * 4 + grp;     // the j this lane's acc computes

    const float* whh = dir ? whh_b : whh_f;
    const float* xg  = dir ? xg_b  : xg_f;
    float* hs        = dir ? hs_b  : hs_f;
    u64* cm          = comm + dir * 2 * HH;

    // A fragments: lane holds A[m=l&15][k=(l>>4)*8 + j], m = jloc*4 + gate.
    // (Any k-map error cancels: same map used for B.)
    short8 afrag[16];
    {
        int m    = l & 15;
        int jloc = m >> 2;
        int g    = m & 3;
        const float* wp = whh + (size_t)(g * HH + j0 + v * 4 + jloc) * HH + (l >> 4) * 8;
        #pragma unroll
        for (int kc = 0; kc < 16; kc++){
            float4 w0 = *reinterpret_cast<const float4*>(wp + kc * 32);
            float4 w1 = *reinterpret_cast<const float4*>(wp + kc * 32 + 4);
            union { unsigned u[4]; short8 s; } fr;
            fr.u[0] = f2bf(w0.x) | (f2bf(w0.y) << 16);
            fr.u[1] = f2bf(w0.z) | (f2bf(w0.w) << 16);
            fr.u[2] = f2bf(w1.x) | (f2bf(w1.y) << 16);
            fr.u[3] = f2bf(w1.z) | (f2bf(w1.w) << 16);
            afrag[kc] = fr.s;
        }
    }

    __shared__ __align__(16) unsigned hb[2][256];   // h as packed bf16 pairs
    float c = 0.f;

    for (int s = 0; s < LL; ++s){
        int t = dir ? (LL - 1 - s) : s;

        // xg for my j (4 gates); issue before poll so it's in flight
        const float* xp = xg + (size_t)t * G4H + jmine;
        float xg0 = xp[0], xg1 = xp[HH], xg2 = xp[2 * HH], xg3 = xp[3 * HH];

        if (s > 0){
            u64* pw = cm + (s & 1) * HH + 2 * tid;
            u64 va = lda(pw), vb = lda(pw + 1);
            unsigned want = (unsigned)s;
            for (;;){
                bool ok = ((unsigned)(va >> 32) == want) && ((unsigned)(vb >> 32) == want);
                if (__all(ok)) break;
                if ((unsigned)(va >> 32) != want) va = lda(pw);
                if ((unsigned)(vb >> 32) != want) vb = lda(pw + 1);
            }
            hb[s & 1][tid] = f2bf(__uint_as_float((unsigned)va))
                           | (f2bf(__uint_as_float((unsigned)vb)) << 16);
        }
        __syncthreads();
        // 1 barrier/step is safe: a poller overwrites hb[s&1] next at iter s+2;
        // its poll(s+2) success requires every local wave published tag s+2,
        // which (program order + data dependency through mfma->gates->h) is
        // after that wave's B-frag reads of hb[s&1] at iter s.

        f32x4 acc = {0.f, 0.f, 0.f, 0.f};
        if (s > 0){
            const char* hbase = (const char*)&hb[s & 1][0] + grp * 16;
            #pragma unroll
            for (int kc = 0; kc < 16; kc++){
                short8 bfrag = *reinterpret_cast<const short8*>(hbase + kc * 64);
                acc = __builtin_amdgcn_mfma_f32_16x16x32_bf16(afrag[kc], bfrag, acc, 0, 0, 0);
            }
        }

        float vi = acc[0] + xg0;
        float vf = acc[1] + xg1;
        float vgg = acc[2] + xg2;
        float vo = acc[3] + xg3;
        c = sigf(vf) * c + sigf(vi) * tanhfast(vgg);
        float hv = sigf(vo) * tanhfast(c);

        if ((l & 15) == 0){
            union { float f; unsigned u; } cv; cv.f = hv;
            u64 pk = ((u64)(s + 1) << 32) | (u64)cv.u;
            __hip_atomic_store(cm + ((s + 1) & 1) * HH + jmine, pk,
                               __ATOMIC_RELAXED, __HIP_MEMORY_SCOPE_AGENT);
            hs[(size_t)t * HH + jmine] = hv;
        }
    }
}

// ---------------- K3: feats[t][n] = w_tag[n] . [hf[t], hb[t]] + b_tag[n]
__global__ __launch_bounds__(64) void k3_feats(
    const float* __restrict__ hs_f, const float* __restrict__ hs_b,
    const float* __restrict__ wtag, const float* __restrict__ btag,
    float* __restrict__ feats)
{
    int t = blockIdx.x;
    int lane = threadIdx.x;
    float hreg[16];
    #pragma unroll
    for (int q = 0; q < 16; q++){
        int k = q * 64 + lane;
        hreg[q] = (q < 8) ? hs_f[(long)t * HH + k] : hs_b[(long)t * HH + (k - HH)];
    }
    for (int n = 0; n < TT; n++){
        float a = 0.f;
        #pragma unroll
        for (int q = 0; q < 16; q++){
            a += wtag[n * 1024 + q * 64 + lane] * hreg[q];
        }
        #pragma unroll
        for (int off = 32; off; off >>= 1) a += __shfl_down(a, off, 64);
        if (lane == 0) feats[t * 12 + n] = a + btag[n];
    }
}

// ---------------- K4a: per-chunk max-plus products P_c[n][s] (64 chunks of 64)
__global__ __launch_bounds__(64) void k4a_chunk(
    const float* __restrict__ feats, const float* __restrict__ trans,
    float* __restrict__ Pmat)
{
    int c = blockIdx.x;
    int lane = threadIdx.x;             // lane = start state s (active < TT)
    float tr[TT][TT];
    #pragma unroll
    for (int n = 0; n < TT; n++)
        #pragma unroll
        for (int p = 0; p < TT; p++) tr[n][p] = trans[n * TT + p];

    float pv[TT];
    #pragma unroll
    for (int n = 0; n < TT; n++) pv[n] = (n == lane) ? 0.f : NEGINF;

    for (int i = 0; i < 64; i++){
        int t = c * 64 + i;
        float ft[TT];
        #pragma unroll
        for (int n = 0; n < TT; n++) ft[n] = feats[t * 12 + n];
        float pn[TT];
        #pragma unroll
        for (int n = 0; n < TT; n++){
            float m = tr[n][0] + pv[0];
            #pragma unroll
            for (int p = 1; p < TT; p++) m = fmaxf(m, tr[n][p] + pv[p]);
            pn[n] = m + ft[n];
        }
        #pragma unroll
        for (int n = 0; n < TT; n++) pv[n] = pn[n];
    }
    if (lane < TT){
        #pragma unroll
        for (int n = 0; n < TT; n++) Pmat[(c * TT + n) * TT + lane] = pv[n];
    }
}

// ---------------- K4b: sequential boundary combine (fv before each chunk)
__global__ __launch_bounds__(64) void k4b_bound(
    const float* __restrict__ Pmat, float* __restrict__ fvb)
{
    int lane = threadIdx.x;
    int ln = (lane < TT) ? lane : 0;
    float fv[TT];
    #pragma unroll
    for (int n = 0; n < TT; n++) fv[n] = (n == TSTART) ? 0.f : NEGINF;

    for (int c = 0; c < 64; c++){
        if (lane < TT) fvb[c * TT + lane] = fv[lane];
        float nf = NEGINF;
        #pragma unroll
        for (int s = 0; s < TT; s++)
            nf = fmaxf(nf, Pmat[(c * TT + ln) * TT + s] + fv[s]);
        #pragma unroll
        for (int n = 0; n < TT; n++) fv[n] = __shfl(nf, n, 64);
    }
    if (lane < TT) fvb[64 * TT + lane] = fv[lane];
}

// ---------------- K4c: per-chunk backpointer recompute (nibble-packed u64/step)
__global__ __launch_bounds__(64) void k4c_bp(
    const float* __restrict__ feats, const float* __restrict__ trans,
    const float* __restrict__ fvb, u64* __restrict__ bpw)
{
    int c = blockIdx.x;
    int lane = threadIdx.x;             // lane = next state n (active < TT)
    int ln = (lane < TT) ? lane : 0;
    float trl[TT];
    #pragma unroll
    for (int p = 0; p < TT; p++) trl[p] = trans[ln * TT + p];
    float fv[TT];
    #pragma unroll
    for (int n = 0; n < TT; n++) fv[n] = fvb[c * TT + n];

    for (int i = 0; i < 64; i++){
        int t = c * 64 + i;
        float best = NEGINF; int bp = 0;
        #pragma unroll
        for (int p = 0; p < TT; p++){
            float sp = trl[p] + fv[p];
            if (sp > best){ best = sp; bp = p; }
        }
        if (lane >= TT) bp = 0;
        unsigned lo = (lane < 8) ? ((unsigned)bp << (4 * lane)) : 0u;
        unsigned hi = (lane >= 8 && lane < TT) ? ((unsigned)bp << (4 * (lane - 8))) : 0u;
        #pragma unroll
        for (int off = 1; off < 16; off <<= 1){
            lo |= __shfl_xor(lo, off, 16); hi |= __shfl_xor(hi, off, 16);
        }
        if (lane == 0) bpw[t] = (u64)lo | ((u64)hi << 32);
        float nf = (lane < TT) ? best + feats[t * 12 + ln] : NEGINF;
        #pragma unroll
        for (int n = 0; n < TT; n++) fv[n] = __shfl(nf, n, 64);
    }
}

// ---------------- K4d: terminal + backtrace
__global__ __launch_bounds__(256) void k4d_bt(
    const u64* __restrict__ bpw, const float* __restrict__ fvb,
    const float* __restrict__ trans, float* __restrict__ out)
{
    __shared__ u64 bl[LL];
    int tid = threadIdx.x;
    for (int i = tid; i < LL; i += 256) bl[i] = bpw[i];
    __syncthreads();

    if (tid < 64){
        int lane = tid;
        int ln = (lane < TT) ? lane : 0;
        float term = (lane < TT) ? (fvb[64 * TT + ln] + trans[TSTOP * TT + ln]) : -3.0e38f;
        int idx = (lane < TT) ? lane : 63;
        #pragma unroll
        for (int off = 32; off; off >>= 1){
            float os = __shfl_down(term, off, 64);
            int   oi = __shfl_down(idx,  off, 64);
            if (os > term || (os == term && oi < idx)){ term = os; idx = oi; }
        }
        if (lane == 0){
            out[0] = term;
            int tag = idx;
            out[1 + (LL - 1)] = (float)tag;
            for (int u = LL - 1; u >= 1; --u){
                tag = (int)((bl[u] >> (4 * tag)) & 15ull);
                out[u] = (float)tag;   // out[1 + (u-1)]
            }
        }
    }
}

__global__ void k_dbg(float* out, float v){ out[0] = v; }

extern "C" void kernel_launch(void* const* d_in, const int* in_sizes, int n_in,
                              void* d_out, int out_size, void* d_ws, size_t ws_size,
                              hipStream_t stream)
{
    const int*   sent  = (const int*)  d_in[0];
    const float* emb   = (const float*)d_in[1];
    const float* wih_f = (const float*)d_in[2];
    const float* whh_f = (const float*)d_in[3];
    const float* bih_f = (const float*)d_in[4];
    const float* bhh_f = (const float*)d_in[5];
    const float* wih_b = (const float*)d_in[6];
    const float* whh_b = (const float*)d_in[7];
    const float* bih_b = (const float*)d_in[8];
    const float* bhh_b = (const float*)d_in[9];
    const float* wtag  = (const float*)d_in[10];
    const float* btag  = (const float*)d_in[11];
    const float* trans = (const float*)d_in[12];
    float* out = (float*)d_out;

    char* ws = (char*)d_ws;
    size_t off = 0;
    float* xg_f = (float*)(ws + off); off += (size_t)LL * G4H * 4;
    float* xg_b = (float*)(ws + off); off += (size_t)LL * G4H * 4;
    float* hs_f = (float*)(ws + off); off += (size_t)LL * HH * 4;
    float* hs_b = (float*)(ws + off); off += (size_t)LL * HH * 4;
    float* feats= (float*)(ws + off); off += (size_t)LL * 12 * 4;
    u64* comm   = (u64*)(ws + off);   off += 2 * 2 * HH * 8;
    float* Pmat = (float*)(ws + off); off += (size_t)64 * TT * TT * 4;
    float* fvb  = (float*)(ws + off); off += (size_t)65 * TT * 4 + 64;
    u64* bpw    = (u64*)(ws + off);   off += (size_t)LL * 8;

    if (off > ws_size){
        k_dbg<<<1, 1, 0, stream>>>(out, (float)ws_size);
        return;
    }

    k0_zero<<<8, 256, 0, stream>>>(comm);
    k1_xg<<<dim3(128, 8, 2), 256, 0, stream>>>(sent, emb, wih_f, bih_f, bhh_f,
                                               wih_b, bih_b, bhh_b, xg_f, xg_b);
    k2_lstm<<<64, 256, 0, stream>>>(whh_f, whh_b, xg_f, xg_b, hs_f, hs_b, comm);
    k3_feats<<<LL, 64, 0, stream>>>(hs_f, hs_b, wtag, btag, feats);
    k4a_chunk<<<64, 64, 0, stream>>>(feats, trans, Pmat);
    k4b_bound<<<1, 64, 0, stream>>>(Pmat, fvb);
    k4c_bp<<<64, 64, 0, stream>>>(feats, trans, fvb, bpw);
    k4d_bt<<<1, 256, 0, stream>>>(bpw, fvb, trans, out);
}